// Round 5
// baseline (390.873 us; speedup 1.0000x reference)
//
#include <hip/hip_runtime.h>
#include <math.h>

// Location-aware attention (ESPnet AttLoc), fused single persistent kernel.
// T=50000, ATT=EPROJ=512, DUNITS=1024, CH=10, KW=201, FILTS=100, SCALING=2.
//
// Phases (one kernel, software grid barrier between):
//  P0: conv1d(att_prev) -> ws_aconv[T][12]; dec_z@w_dec.T -> ws_dec; zero c.
//  P1: e[t]=gvec.tanh(pre+dec+aconv@w_att^T) -> ws_e; per-block (max,sumexp).
//  P2: every block merges the 512 partials -> (M, 1/S).
//  P3: w[t]=exp(y-M)/S -> out[512+t]; context partial -> atomicAdd out[0:512].
//
// Grid barrier safety: grid = 512 blocks = exactly 2 blocks/CU on 256 CUs;
// __launch_bounds__(256,2) caps VGPR<=256 and LDS 23KB*2=46KB<=160KB, so all
// 512 blocks are co-resident by construction. Barrier counter is a monotonic
// device-scope atomic in d_ws, reset to 0 each call by hipMemsetAsync
// (capture-safe). __threadfence() gives cross-XCD release/acquire.

constexpr int ATT    = 512;
constexpr int CH     = 10;
constexpr int PCH    = 12;     // padded channel stride (48 B, float4-aligned)
constexpr int KW     = 201;
constexpr int FILTS  = 100;
constexpr int DUNITS = 1024;
constexpr int NBLK   = 512;    // 2 blocks/CU -> co-residency guaranteed
constexpr int CT     = 64;     // t-tile per conv tile
constexpr float SCALING = 2.0f;

__device__ __forceinline__ float wave_reduce_sum(float v) {
    #pragma unroll
    for (int off = 32; off > 0; off >>= 1) v += __shfl_xor(v, off, 64);
    return v;
}

__device__ __forceinline__ float fast_tanh(float x) {
    x = fminf(fmaxf(x, -15.f), 15.f);
    float e = __expf(2.f * x);
    return __fdividef(e - 1.f, e + 1.f);
}

struct ConvS {
    float ap[CT + KW - 1];   // 264
    float wt[KW * 12];       // 2412, transposed [k][c] pad 12
    float part[4 * CT * CH]; // 2560
};

union alignas(16) ShU {
    ConvS conv;              // 20.9 KB (P0)
    float watt[ATT * CH];    // 20.5 KB (P1)
    float c[4 * ATT];        // 8 KB   (P3)
};

__device__ __forceinline__ void grid_barrier(unsigned* bar, unsigned target) {
    __syncthreads();
    if (threadIdx.x == 0) {
        __threadfence();                      // release: publish our writes
        atomicAdd(bar, 1u);                   // device-scope by default
        while (__hip_atomic_load(bar, __ATOMIC_ACQUIRE,
                                 __HIP_MEMORY_SCOPE_AGENT) < target)
            __builtin_amdgcn_s_sleep(2);
        __threadfence();                      // acquire: invalidate stale lines
    }
    __syncthreads();
}

__global__ __launch_bounds__(256, 2) void fused_attloc(
    const float* __restrict__ dec_z,
    const float* __restrict__ att_prev,
    const float* __restrict__ pre,       // [T][512]
    const float* __restrict__ enc_h,     // [T][512]
    const float* __restrict__ mask,      // [T]
    const float* __restrict__ conv_w,    // [CH][1][KW]
    const float* __restrict__ w_att,     // [512][10]
    const float* __restrict__ w_dec,     // [512][1024]
    const float* __restrict__ w_gvec,    // [512]
    const float* __restrict__ b_gvec,    // [1]
    float* __restrict__ out,             // [0:512)=c, [512:512+T)=w
    float* __restrict__ ws_dec,          // [512]
    float* __restrict__ ws_aconv,        // [T][PCH]
    float* __restrict__ ws_e,            // [T]
    float* __restrict__ ws_ms,           // [NBLK*2]
    unsigned* __restrict__ bar,
    int T, int nbconv)
{
    __shared__ ShU u;
    __shared__ float s_m[256], s_s[256];
    const int tid  = threadIdx.x;
    const int bid  = blockIdx.x;
    const int wid  = tid >> 6;
    const int lane = tid & 63;

    // ================= P0: conv + dec projection + zero c =================
    // transposed conv weights, loaded once
    for (int i = tid; i < CH * KW; i += 256) {
        int c = i % CH, k = i / CH;
        u.conv.wt[k * 12 + c] = conv_w[c * KW + k];
    }
    for (int tile = bid; tile < nbconv; tile += NBLK) {
        const int t0 = tile * CT;
        __syncthreads();   // wt ready (iter 0) / prev part consumed
        for (int i = tid; i < CT + KW - 1; i += 256) {
            int t = t0 - FILTS + i;
            u.conv.ap[i] = (t >= 0 && t < T) ? att_prev[t] : 0.f;
        }
        __syncthreads();
        float acc[CH];
        #pragma unroll
        for (int c = 0; c < CH; ++c) acc[c] = 0.f;
        // taps k ≡ wid (mod 4); all lanes of a wave share k -> LDS broadcast
        for (int k = wid; k < KW; k += 4) {
            float x = u.conv.ap[lane + k];
            const float4 w0 = *(const float4*)&u.conv.wt[k * 12];
            const float4 w1 = *(const float4*)&u.conv.wt[k * 12 + 4];
            const float2 w2 = *(const float2*)&u.conv.wt[k * 12 + 8];
            acc[0] += x * w0.x; acc[1] += x * w0.y;
            acc[2] += x * w0.z; acc[3] += x * w0.w;
            acc[4] += x * w1.x; acc[5] += x * w1.y;
            acc[6] += x * w1.z; acc[7] += x * w1.w;
            acc[8] += x * w2.x; acc[9] += x * w2.y;
        }
        #pragma unroll
        for (int c = 0; c < CH; ++c)
            u.conv.part[wid * (CT * CH) + lane * CH + c] = acc[c];
        __syncthreads();
        for (int idx = tid; idx < CT * PCH; idx += 256) {
            int tt = idx / PCH, c = idx % PCH;
            float v = 0.f;
            if (c < CH) {
                int j = tt * CH + c;
                v = u.conv.part[j] + u.conv.part[CT * CH + j]
                  + u.conv.part[2 * CT * CH + j] + u.conv.part[3 * CT * CH + j];
            }
            if (t0 + tt < T) ws_aconv[(size_t)(t0 + tt) * PCH + c] = v;
        }
    }
    // dec projection: blocks 0..127, one wave per output dim
    if (bid < ATT / 4) {
        const int a = bid * 4 + wid;
        const float4* wd = (const float4*)(w_dec + (size_t)a * DUNITS);
        const float4* dz = (const float4*)dec_z;
        float acc = 0.f;
        #pragma unroll
        for (int q = 0; q < 4; ++q) {
            float4 wv = wd[lane + q * 64];
            float4 zv = dz[lane + q * 64];
            acc += wv.x * zv.x + wv.y * zv.y + wv.z * zv.z + wv.w * zv.w;
        }
        acc = wave_reduce_sum(acc);
        if (lane == 0) ws_dec[a] = acc;
    }
    if (bid == NBLK - 1)
        for (int i = tid; i < ATT; i += 256) out[i] = 0.f;

    grid_barrier(bar, NBLK);

    // ================= P1: scores =================
    for (int i = tid; i < ATT * CH; i += 256) u.watt[i] = w_att[i];
    __syncthreads();

    float wa[8][CH];
    #pragma unroll
    for (int j = 0; j < 4; ++j) {
        #pragma unroll
        for (int c = 0; c < CH; ++c) {
            wa[j][c]     = u.watt[(lane * 4 + j) * CH + c];
            wa[4 + j][c] = u.watt[(256 + lane * 4 + j) * CH + c];
        }
    }
    const float4 dlo = ((const float4*)ws_dec)[lane];
    const float4 dhi = ((const float4*)ws_dec)[64 + lane];
    const float4 glo = ((const float4*)w_gvec)[lane];
    const float4 ghi = ((const float4*)w_gvec)[64 + lane];
    const float  bg  = b_gvec[0];

    float m = -INFINITY, s = 0.f;
    const float4* pre4 = (const float4*)pre;
    const float4* ac4  = (const float4*)ws_aconv;   // 3 float4 per t
    const int gw = bid * 4 + wid;

    for (int tb = gw * 4; tb < T; tb += NBLK * 16) {
        float4 p0[4], p1[4];
        float  msk[4];
        #pragma unroll
        for (int i = 0; i < 4; ++i) {
            int t = tb + i;
            if (t < T) {
                p0[i]  = pre4[(size_t)t * 128 + lane];
                p1[i]  = pre4[(size_t)t * 128 + 64 + lane];
                msk[i] = mask[t];
            }
        }
        #pragma unroll
        for (int i = 0; i < 4; ++i) {
            int t = tb + i;
            if (t >= T) break;
            float ac[12];
            *(float4*)&ac[0] = ac4[(size_t)t * 3 + 0];
            *(float4*)&ac[4] = ac4[(size_t)t * 3 + 1];
            *(float4*)&ac[8] = ac4[(size_t)t * 3 + 2];
            float av[8];
            #pragma unroll
            for (int j = 0; j < 8; ++j) {
                float v = 0.f;
                #pragma unroll
                for (int c = 0; c < CH; ++c) v += ac[c] * wa[j][c];
                av[j] = v;
            }
            float x0 = fast_tanh(p0[i].x + dlo.x + av[0]);
            float x1 = fast_tanh(p0[i].y + dlo.y + av[1]);
            float x2 = fast_tanh(p0[i].z + dlo.z + av[2]);
            float x3 = fast_tanh(p0[i].w + dlo.w + av[3]);
            float x4 = fast_tanh(p1[i].x + dhi.x + av[4]);
            float x5 = fast_tanh(p1[i].y + dhi.y + av[5]);
            float x6 = fast_tanh(p1[i].z + dhi.z + av[6]);
            float x7 = fast_tanh(p1[i].w + dhi.w + av[7]);
            float acc = glo.x * x0 + glo.y * x1 + glo.z * x2 + glo.w * x3
                      + ghi.x * x4 + ghi.y * x5 + ghi.z * x6 + ghi.w * x7;
            acc = wave_reduce_sum(acc);
            float y = SCALING * (acc + bg + msk[i]);
            if (lane == 0) ws_e[t] = y;
            float nm = fmaxf(m, y);
            s = s * __expf(m - nm) + __expf(y - nm);
            m = nm;
        }
    }
    if (lane == 0) { s_m[wid] = m; s_s[wid] = s; }
    __syncthreads();
    if (tid == 0) {
        float M = s_m[0], S = s_s[0];
        #pragma unroll
        for (int w = 1; w < 4; ++w) {
            float m2 = s_m[w], s2 = s_s[w];
            float nm = fmaxf(M, m2);
            S = S * __expf(M - nm) + s2 * __expf(m2 - nm);
            M = nm;
        }
        ws_ms[bid * 2]     = M;
        ws_ms[bid * 2 + 1] = S;
    }

    grid_barrier(bar, 2 * NBLK);

    // ================= P2: every block merges 512 partials =================
    {
        float mm = -INFINITY, ss = 0.f;
        for (int i = tid; i < NBLK; i += 256) {
            float m2 = ws_ms[i * 2], s2 = ws_ms[i * 2 + 1];
            float nm = fmaxf(mm, m2);
            ss = ss * __expf(mm - nm) + s2 * __expf(m2 - nm);
            mm = nm;
        }
        s_m[tid] = mm; s_s[tid] = ss;
        __syncthreads();
        for (int off = 128; off > 0; off >>= 1) {
            if (tid < off) {
                float M1 = s_m[tid], S1 = s_s[tid];
                float m2 = s_m[tid + off], s2 = s_s[tid + off];
                float nm = fmaxf(M1, m2);
                s_s[tid] = S1 * __expf(M1 - nm) + s2 * __expf(m2 - nm);
                s_m[tid] = nm;
            }
            __syncthreads();
        }
    }
    const float M  = s_m[0];
    const float IS = 1.f / s_s[0];

    // ================= P3: weights + context =================
    float4 a0 = make_float4(0.f, 0.f, 0.f, 0.f);
    float4 a1 = make_float4(0.f, 0.f, 0.f, 0.f);
    const float4* eh4 = (const float4*)enc_h;

    for (int tb = gw * 4; tb < T; tb += NBLK * 16) {
        float4 e0[4], e1[4];
        float  y[4];
        #pragma unroll
        for (int i = 0; i < 4; ++i) {
            int t = tb + i;
            if (t < T) {
                e0[i] = eh4[(size_t)t * 128 + lane];
                e1[i] = eh4[(size_t)t * 128 + 64 + lane];
                y[i]  = ws_e[t];
            }
        }
        #pragma unroll
        for (int i = 0; i < 4; ++i) {
            int t = tb + i;
            if (t >= T) break;
            float w = __expf(y[i] - M) * IS;
            if (lane == 0) out[ATT + t] = w;
            a0.x += w * e0[i].x; a0.y += w * e0[i].y;
            a0.z += w * e0[i].z; a0.w += w * e0[i].w;
            a1.x += w * e1[i].x; a1.y += w * e1[i].y;
            a1.z += w * e1[i].z; a1.w += w * e1[i].w;
        }
    }

    __syncthreads();   // everyone past P2 reads of s_m/s_s before u.c reuse
    float4* s_c4 = (float4*)u.c;
    s_c4[wid * 128 + lane]      = a0;
    s_c4[wid * 128 + 64 + lane] = a1;
    __syncthreads();
    const float* sc = u.c;
    for (int a = tid; a < ATT; a += 256) {
        float v = sc[a] + sc[512 + a] + sc[1024 + a] + sc[1536 + a];
        atomicAdd(&out[a], v);
    }
}

extern "C" void kernel_launch(void* const* d_in, const int* in_sizes, int n_in,
                              void* d_out, int out_size, void* d_ws, size_t ws_size,
                              hipStream_t stream)
{
    const float* dec_z    = (const float*)d_in[0];
    const float* att_prev = (const float*)d_in[1];
    const float* pre      = (const float*)d_in[2];
    const float* enc_h    = (const float*)d_in[3];
    const float* mask     = (const float*)d_in[4];
    const float* conv_w   = (const float*)d_in[5];
    const float* w_att    = (const float*)d_in[6];
    const float* w_dec    = (const float*)d_in[7];
    const float* w_gvec   = (const float*)d_in[8];
    const float* b_gvec   = (const float*)d_in[9];
    const int T = in_sizes[1];

    unsigned* bar   = (unsigned*)d_ws;             // 64 B reserved
    float* ws       = (float*)d_ws + 16;
    float* ws_dec   = ws;                          // 512
    float* ws_aconv = ws_dec + ATT;                // T*PCH
    float* ws_e     = ws_aconv + (size_t)T * PCH;  // T
    float* ws_ms    = ws_e + T;                    // NBLK*2
    float* out      = (float*)d_out;

    const int nbconv = (T + CT - 1) / CT;

    hipMemsetAsync(bar, 0, 64, stream);            // reset barrier (capture-safe)
    hipLaunchKernelGGL(fused_attloc, dim3(NBLK), dim3(256), 0, stream,
                       dec_z, att_prev, pre, enc_h, mask, conv_w, w_att, w_dec,
                       w_gvec, b_gvec, out, ws_dec, ws_aconv, ws_e, ws_ms,
                       bar, T, nbconv);
}

// Round 7
// 298.987 us; speedup vs baseline: 1.3073x; 1.3073x over previous
//
#include <hip/hip_runtime.h>
#include <math.h>

// Location-aware attention (ESPnet AttLoc), T=50000, ATT=EPROJ=512, DUNITS=1024,
// CH=10, KW=201, FILTS=100, SCALING=2.  Split 3-kernel pipeline (fused persistent
// version was 2x SLOWER: occupancy halved by co-residency cap — R5 post-mortem).
//
// K0: conv1d(att_prev) -> ws_aconv[T][12]; dec_z@w_dec.T -> ws_dec; zero out[0:512].
// K1: scores. w_att held in REGISTERS loaded from global (NO LDS copy — R5 showed
//     the compiler demotes an LDS-backed wa[8][10] to per-use ds_read, ~460cyc/t).
//     A/B register prefetch of pre; batched softmax partials -> ws_e, ws_ms.
// K3: per-block merge of ws_ms -> (M,1/S); w=exp(y-M)/S -> out[512+t]; context
//     partials with A/B prefetch -> atomicAdd out[0:512].

constexpr int ATT    = 512;
constexpr int CH     = 10;
constexpr int PCH    = 12;     // padded channel stride (48 B, float4-aligned)
constexpr int KW     = 201;
constexpr int FILTS  = 100;
constexpr int DUNITS = 1024;
constexpr int NB1    = 1024;   // K1 grid
constexpr int NB3    = 1024;   // K3 grid
constexpr int CT     = 64;     // t-tile per conv block
constexpr float SCALING = 2.0f;

__device__ __forceinline__ float wave_reduce_sum(float v) {
    #pragma unroll
    for (int off = 32; off > 0; off >>= 1) v += __shfl_xor(v, off, 64);
    return v;
}

// tanh(x) = 1 - 2/(e^{2x}+1): clamp-free, NaN-safe (e=inf -> 1, e=0 -> -1)
__device__ __forceinline__ float fast_tanh(float x) {
    float e = __expf(2.f * x);
    return 1.f - __fdividef(2.f, e + 1.f);
}

// ---------------- K0: conv over att_prev + dec projection + zero c ----------------
__global__ __launch_bounds__(256, 4) void k0_conv_dec(
    const float* __restrict__ att_prev,
    const float* __restrict__ conv_w,   // [CH][1][KW]
    const float* __restrict__ dec_z,    // [DUNITS]
    const float* __restrict__ w_dec,    // [ATT][DUNITS]
    float* __restrict__ ws_aconv,       // [T][PCH]
    float* __restrict__ ws_dec,         // [ATT]
    float* __restrict__ out,            // d_out (zero [0:512))
    int T, int nbconv)
{
    if ((int)blockIdx.x < nbconv) {
        __shared__ float s_ap[CT + KW - 1];     // 264
        __shared__ float s_wt[KW * 12];         // transposed weights [k][c], pad 12
        __shared__ float s_part[4 * CT * CH];   // per-wave partials
        const int t0 = blockIdx.x * CT;
        for (int i = threadIdx.x; i < CT + KW - 1; i += 256) {
            int t = t0 - FILTS + i;
            s_ap[i] = (t >= 0 && t < T) ? att_prev[t] : 0.f;
        }
        for (int i = threadIdx.x; i < CH * KW; i += 256) {
            int c = i % CH, k = i / CH;
            s_wt[k * 12 + c] = conv_w[c * KW + k];
        }
        __syncthreads();
        const int tl = threadIdx.x & 63;   // t within tile
        const int kq = threadIdx.x >> 6;   // tap quarter (wave id)
        float acc[CH];
        #pragma unroll
        for (int c = 0; c < CH; ++c) acc[c] = 0.f;
        for (int k = kq; k < KW; k += 4) {
            float x = s_ap[tl + k];
            const float4 w0 = *(const float4*)&s_wt[k * 12];
            const float4 w1 = *(const float4*)&s_wt[k * 12 + 4];
            const float2 w2 = *(const float2*)&s_wt[k * 12 + 8];
            acc[0] += x * w0.x; acc[1] += x * w0.y;
            acc[2] += x * w0.z; acc[3] += x * w0.w;
            acc[4] += x * w1.x; acc[5] += x * w1.y;
            acc[6] += x * w1.z; acc[7] += x * w1.w;
            acc[8] += x * w2.x; acc[9] += x * w2.y;
        }
        #pragma unroll
        for (int c = 0; c < CH; ++c) s_part[kq * (CT * CH) + tl * CH + c] = acc[c];
        __syncthreads();
        for (int idx = threadIdx.x; idx < CT * PCH; idx += 256) {
            int t = idx / PCH, c = idx % PCH;
            float v = 0.f;
            if (c < CH) {
                int j = t * CH + c;
                v = s_part[j] + s_part[CT * CH + j]
                  + s_part[2 * CT * CH + j] + s_part[3 * CT * CH + j];
            }
            if (t0 + t < T) ws_aconv[(size_t)(t0 + t) * PCH + c] = v;
        }
    } else {
        const int b    = blockIdx.x - nbconv;          // 0..127
        const int wid  = threadIdx.x >> 6;
        const int lane = threadIdx.x & 63;
        const int a    = b * 4 + wid;                  // 0..511
        if (threadIdx.x < 4) out[b * 4 + threadIdx.x] = 0.f;
        const float4* wd = (const float4*)(w_dec + (size_t)a * DUNITS);
        const float4* dz = (const float4*)dec_z;
        float acc = 0.f;
        #pragma unroll
        for (int q = 0; q < 4; ++q) {
            float4 wv = wd[lane + q * 64];
            float4 zv = dz[lane + q * 64];
            acc += wv.x * zv.x + wv.y * zv.y + wv.z * zv.z + wv.w * zv.w;
        }
        acc = wave_reduce_sum(acc);
        if (lane == 0) ws_dec[a] = acc;
    }
}

// ---------------- K1: scores ----------------
__global__ __launch_bounds__(256, 2) void k1_scores(
    const float* __restrict__ pre,       // [T][512]
    const float* __restrict__ mask,      // [T]
    const float* __restrict__ w_att,     // [512][10]
    const float* __restrict__ w_gvec,    // [512]
    const float* __restrict__ b_gvec,    // [1]
    const float* __restrict__ ws_dec,    // [512]
    const float* __restrict__ ws_aconv,  // [T][PCH]
    float* __restrict__ ws_e,            // [T]
    float* __restrict__ ws_ms,           // [NB1*2]
    int T)
{
    __shared__ float s_m[4], s_s[4];
    const int wid  = threadIdx.x >> 6;
    const int lane = threadIdx.x & 63;

    // lane owns a-dims: j<4 -> lane*4+j ; j>=4 -> 256+lane*4+(j-4).
    // Loaded from GLOBAL into registers — deliberately no LDS copy, so the
    // compiler has no cheap re-read source and must keep wa in VGPRs.
    float wa[8][CH];
    #pragma unroll
    for (int j = 0; j < 4; ++j) {
        #pragma unroll
        for (int c = 0; c < CH; ++c) {
            wa[j][c]     = w_att[(lane * 4 + j) * CH + c];
            wa[4 + j][c] = w_att[(256 + lane * 4 + j) * CH + c];
        }
    }
    const float4 dlo = ((const float4*)ws_dec)[lane];
    const float4 dhi = ((const float4*)ws_dec)[64 + lane];
    const float4 glo = ((const float4*)w_gvec)[lane];
    const float4 ghi = ((const float4*)w_gvec)[64 + lane];
    const float  bg  = b_gvec[0];

    const float4* pre4 = (const float4*)pre;
    const float4* ac4  = (const float4*)ws_aconv;   // 3 float4 per t
    const int gw = blockIdx.x * 4 + wid;
    const int t0 = gw * 4;
    constexpr int S = NB1 * 16;                     // 16384; 4 batches cover T

    float m = -INFINITY, s = 0.f;
    float4 pA0[4], pA1[4], pB0[4], pB1[4];
    float  mA[4], mB[4];
    float4 acx[4], acy[4], acz[4];                  // aconv[t][0..11], uniform

    auto loadp = [&](float4 (&P0)[4], float4 (&P1)[4], float (&MSK)[4], int tb) {
        #pragma unroll
        for (int i = 0; i < 4; ++i) {
            int t = tb + i;
            if (t < T) {
                P0[i]  = pre4[(size_t)t * 128 + lane];
                P1[i]  = pre4[(size_t)t * 128 + 64 + lane];
                MSK[i] = mask[t];
            }
        }
    };
    auto loada = [&](int tb) {
        #pragma unroll
        for (int i = 0; i < 4; ++i) {
            int t = tb + i;
            if (t < T) {
                acx[i] = ac4[(size_t)t * 3 + 0];
                acy[i] = ac4[(size_t)t * 3 + 1];
                acz[i] = ac4[(size_t)t * 3 + 2];
            }
        }
    };
    auto batch = [&](float4 (&P0)[4], float4 (&P1)[4], float (&MSK)[4], int tb,
                     float4 (&NP0)[4], float4 (&NP1)[4], float (&NM)[4], int tn,
                     bool pf) {
        if (pf) loadp(NP0, NP1, NM, tn);   // next pre batch in flight over compute
        float y[4];
        #pragma unroll
        for (int i = 0; i < 4; ++i) {
            const int t = tb + i;
            y[i] = -INFINITY;
            if (t < T) {
                const float4 a0 = acx[i], a1 = acy[i], a2 = acz[i];
                float x0 = P0[i].x + dlo.x, x1 = P0[i].y + dlo.y;
                float x2 = P0[i].z + dlo.z, x3 = P0[i].w + dlo.w;
                float x4 = P1[i].x + dhi.x, x5 = P1[i].y + dhi.y;
                float x6 = P1[i].z + dhi.z, x7 = P1[i].w + dhi.w;
                #define AV(X, J) \
                    X += a0.x*wa[J][0] + a0.y*wa[J][1] + a0.z*wa[J][2] + a0.w*wa[J][3] \
                       + a1.x*wa[J][4] + a1.y*wa[J][5] + a1.z*wa[J][6] + a1.w*wa[J][7] \
                       + a2.x*wa[J][8] + a2.y*wa[J][9]
                AV(x0, 0); AV(x1, 1); AV(x2, 2); AV(x3, 3);
                AV(x4, 4); AV(x5, 5); AV(x6, 6); AV(x7, 7);
                #undef AV
                float acc = glo.x * fast_tanh(x0) + glo.y * fast_tanh(x1)
                          + glo.z * fast_tanh(x2) + glo.w * fast_tanh(x3)
                          + ghi.x * fast_tanh(x4) + ghi.y * fast_tanh(x5)
                          + ghi.z * fast_tanh(x6) + ghi.w * fast_tanh(x7);
                acc = wave_reduce_sum(acc);
                float yy = SCALING * (acc + bg + MSK[i]);
                if (lane == 0) ws_e[t] = yy;
                y[i] = yy;
            }
        }
        if (pf) loada(tn);                 // aconv regs dead now; reload for next
        // batched online softmax: 4 independent exps, one chain step per batch
        float ymax = fmaxf(fmaxf(y[0], y[1]), fmaxf(y[2], y[3]));
        float nm = fmaxf(m, ymax);
        float add = __expf(y[0] - nm) + __expf(y[1] - nm)
                  + __expf(y[2] - nm) + __expf(y[3] - nm);
        s = s * __expf(m - nm) + add;
        m = nm;
    };

    loadp(pA0, pA1, mA, t0);
    loada(t0);
    batch(pA0, pA1, mA, t0,         pB0, pB1, mB, t0 + S,     true);
    batch(pB0, pB1, mB, t0 + S,     pA0, pA1, mA, t0 + 2 * S, true);
    batch(pA0, pA1, mA, t0 + 2 * S, pB0, pB1, mB, t0 + 3 * S, true);
    batch(pB0, pB1, mB, t0 + 3 * S, pA0, pA1, mA, 0,          false);

    if (lane == 0) { s_m[wid] = m; s_s[wid] = s; }
    __syncthreads();
    if (threadIdx.x == 0) {
        float M = s_m[0], Ssum = s_s[0];
        #pragma unroll
        for (int w = 1; w < 4; ++w) {
            float m2 = s_m[w], s2 = s_s[w];
            float nm = fmaxf(M, m2);
            Ssum = Ssum * __expf(M - nm) + s2 * __expf(m2 - nm);
            M = nm;
        }
        ws_ms[blockIdx.x * 2]     = M;
        ws_ms[blockIdx.x * 2 + 1] = Ssum;
    }
}

// ---------------- K3: merge partials + weights + context ----------------
__global__ __launch_bounds__(256, 4) void k3_ctx(
    const float* __restrict__ enc_h,     // [T][512]
    const float* __restrict__ ws_e,      // [T]
    const float* __restrict__ ws_ms,     // [NB1*2]
    float* __restrict__ out,             // [0:512)=c (pre-zeroed), [512:512+T)=w
    int T)
{
    __shared__ float s_m[256], s_s[256];
    {
        float m = -INFINITY, s = 0.f;
        for (int i = threadIdx.x; i < NB1; i += 256) {
            float m2 = ws_ms[i * 2], s2 = ws_ms[i * 2 + 1];
            float nm = fmaxf(m, m2);
            s = s * __expf(m - nm) + s2 * __expf(m2 - nm);
            m = nm;
        }
        s_m[threadIdx.x] = m; s_s[threadIdx.x] = s;
        __syncthreads();
        for (int off = 128; off > 0; off >>= 1) {
            if ((int)threadIdx.x < off) {
                float M1 = s_m[threadIdx.x], S1 = s_s[threadIdx.x];
                float m2 = s_m[threadIdx.x + off], s2 = s_s[threadIdx.x + off];
                float nm = fmaxf(M1, m2);
                s_s[threadIdx.x] = S1 * __expf(M1 - nm) + s2 * __expf(m2 - nm);
                s_m[threadIdx.x] = nm;
            }
            __syncthreads();
        }
    }
    const float M  = s_m[0];
    const float IS = 1.f / s_s[0];

    const int wid  = threadIdx.x >> 6;
    const int lane = threadIdx.x & 63;
    const float4* eh4 = (const float4*)enc_h;
    const int gw = blockIdx.x * 4 + wid;
    const int t0 = gw * 4;
    constexpr int S = NB3 * 16;         // 16384; 4 batches cover T

    float4 a0 = make_float4(0.f, 0.f, 0.f, 0.f);
    float4 a1 = make_float4(0.f, 0.f, 0.f, 0.f);
    float4 eA0[4], eA1[4], eB0[4], eB1[4];
    float  yA[4], yB[4];

    auto loade = [&](float4 (&E0)[4], float4 (&E1)[4], float (&Y)[4], int tb) {
        #pragma unroll
        for (int i = 0; i < 4; ++i) {
            int t = tb + i;
            if (t < T) {
                E0[i] = eh4[(size_t)t * 128 + lane];
                E1[i] = eh4[(size_t)t * 128 + 64 + lane];
                Y[i]  = ws_e[t];
            }
        }
    };
    auto batch = [&](float4 (&E0)[4], float4 (&E1)[4], float (&Y)[4], int tb,
                     float4 (&NE0)[4], float4 (&NE1)[4], float (&NY)[4], int tn,
                     bool pf) {
        if (pf) loade(NE0, NE1, NY, tn);   // next batch in flight over compute
        #pragma unroll
        for (int i = 0; i < 4; ++i) {
            int t = tb + i;
            if (t < T) {
                float w = __expf(Y[i] - M) * IS;
                if (lane == 0) out[ATT + t] = w;
                a0.x += w * E0[i].x; a0.y += w * E0[i].y;
                a0.z += w * E0[i].z; a0.w += w * E0[i].w;
                a1.x += w * E1[i].x; a1.y += w * E1[i].y;
                a1.z += w * E1[i].z; a1.w += w * E1[i].w;
            }
        }
    };

    loade(eA0, eA1, yA, t0);
    batch(eA0, eA1, yA, t0,         eB0, eB1, yB, t0 + S,     true);
    batch(eB0, eB1, yB, t0 + S,     eA0, eA1, yA, t0 + 2 * S, true);
    batch(eA0, eA1, yA, t0 + 2 * S, eB0, eB1, yB, t0 + 3 * S, true);
    batch(eB0, eB1, yB, t0 + 3 * S, eA0, eA1, yA, 0,          false);

    __syncthreads();
    __shared__ float4 s_c[4 * 128];   // 8 KiB = [wave][512 floats]
    s_c[wid * 128 + lane]      = a0;
    s_c[wid * 128 + 64 + lane] = a1;
    __syncthreads();
    const float* sc = (const float*)s_c;
    for (int a = threadIdx.x; a < ATT; a += 256) {
        float v = sc[a] + sc[512 + a] + sc[1024 + a] + sc[1536 + a];
        atomicAdd(&out[a], v);
    }
}

extern "C" void kernel_launch(void* const* d_in, const int* in_sizes, int n_in,
                              void* d_out, int out_size, void* d_ws, size_t ws_size,
                              hipStream_t stream)
{
    const float* dec_z    = (const float*)d_in[0];
    const float* att_prev = (const float*)d_in[1];
    const float* pre      = (const float*)d_in[2];
    const float* enc_h    = (const float*)d_in[3];
    const float* mask     = (const float*)d_in[4];
    const float* conv_w   = (const float*)d_in[5];
    const float* w_att    = (const float*)d_in[6];
    const float* w_dec    = (const float*)d_in[7];
    const float* w_gvec   = (const float*)d_in[8];
    const float* b_gvec   = (const float*)d_in[9];
    const int T = in_sizes[1];

    float* ws       = (float*)d_ws;
    float* ws_dec   = ws;                          // 512
    float* ws_aconv = ws_dec + ATT;                // T*PCH (16B-aligned: 2048B off)
    float* ws_e     = ws_aconv + (size_t)T * PCH;  // T
    float* ws_ms    = ws_e + T;                    // NB1*2
    float* out      = (float*)d_out;

    const int nbconv = (T + CT - 1) / CT;

    hipLaunchKernelGGL(k0_conv_dec, dim3(nbconv + ATT / 4), dim3(256), 0, stream,
                       att_prev, conv_w, dec_z, w_dec, ws_aconv, ws_dec, out, T, nbconv);
    hipLaunchKernelGGL(k1_scores, dim3(NB1), dim3(256), 0, stream,
                       pre, mask, w_att, w_gvec, b_gvec, ws_dec, ws_aconv,
                       ws_e, ws_ms, T);
    hipLaunchKernelGGL(k3_ctx, dim3(NB3), dim3(256), 0, stream,
                       enc_h, ws_e, ws_ms, out, T);
}